// Round 16
// baseline (29.975 us; speedup 1.0000x reference)
//
#include <hip/hip_runtime.h>
#include <hip/hip_bf16.h>
#include <math.h>

// Problem constants (fixed by the reference's setup_inputs)
#define N_STATE 1024
#define N_HEAD  16
#define H_DIM   64          // N_STATE / N_HEAD
#define NUM_ROT 8
#define SEQ     4096
#define HVPB    128         // head-vectors per tile
#define TILES   4           // tiles per block (r16: 2 -> 4, grid 512)

typedef __attribute__((ext_vector_type(8))) short bf16x8;
typedef __attribute__((ext_vector_type(4))) float f32x4;

// scalar float -> bf16 (round-to-nearest-even) — cold path
__device__ __forceinline__ unsigned short f2bf(float f) {
    union { float f; unsigned u; } v; v.f = f;
    unsigned r = v.u + 0x7fffu + ((v.u >> 16) & 1u);
    return (unsigned short)(r >> 16);
}
// packed pair convert via v_cvt_pk_bf16_f32 — hot path
__device__ __forceinline__ unsigned cvtpk(float a, float b) {
    union { __hip_bfloat162 h; unsigned u; } p;
    p.h = __float22bfloat162_rn(make_float2(a, b));
    return p.u;
}
__device__ __forceinline__ bf16x8 cvt8(const float4 lo, const float4 hi) {
    union { bf16x8 v; unsigned u[4]; } r;
    r.u[0] = cvtpk(lo.x, lo.y);
    r.u[1] = cvtpk(lo.z, lo.w);
    r.u[2] = cvtpk(hi.x, hi.y);
    r.u[3] = cvtpk(hi.z, hi.w);
    return r.v;
}

#define RF_STRIDE 68   // floats per row of Rf (64 + 4 pad)
#define RT_STRIDE 72   // shorts per row of Rt_s
// Static LDS layout (bytes):
//   [0     , 17408) Rf f32[64][68] (compose only) | overlay: snc f32[4][8][64] at [0,8192)
//   [17408 , 26624) Rt_s bf16[64][72]  permuted R^T, live whole kernel
//   [26624 , 26688) csh: 8 x (cos,sin)
//   [26688 , 26752) prs: 16 ints
#define SM_TOTAL 26752

// ---------------------------------------------------------------------------
// r11 structure exactly, TILES=4: grid 512, compose count halved (512).
//  entry: chunks 0,1 x loads issued immediately (compose hides latency).
//  A) per-block redundant compose: M direct from global (L2-hot), Givens
//     barrier-free, R@M on matrix pipe, permuted bf16 R^T to LDS.
//  B) 4 tiles x 2 chunks: B-frags direct from global (contiguous-in-K per
//     lane), packed cvt_pk, MFMA, in-register RoPE, full-line f4 stores.
//     2-chunk-deep rolling lookahead (prefetch c+2 during c).
// ---------------------------------------------------------------------------
__global__ __launch_bounds__(256, 4)
void rope_fused_kernel(const float* __restrict__ x,
                       const float* __restrict__ thetas,
                       const float* __restrict__ pairs,
                       const float* __restrict__ theta_scale,
                       const float* __restrict__ M,
                       const float* __restrict__ inv_freq,
                       float* __restrict__ out,
                       int nb)                       // blocks in grid
{
    __shared__ __align__(16) char smem[SM_TOTAL];
    float*          Rf   = (float*)(smem);
    unsigned short* Rt_s = (unsigned short*)(smem + 17408);
    float*          csh  = (float*)(smem + 26624);
    int*            prs  = (int*)(smem + 26688);
    float*          snc  = (float*)(smem);                    // overlay (Rf dead)

    const int t   = threadIdx.x;
    const int w   = t >> 6;
    const int l   = t & 63;
    const int r16 = l & 15;
    const int q4  = l >> 4;
    const int bid = blockIdx.x;

    // ---- entry: issue x loads for chunks 0 and 1 (compose hides latency) ----
    float4 xa[4], xb[4];
    {
        const size_t rA = (size_t)bid * HVPB + w * 32;          // c0: tt0,nt0
        const float* pA = x + (rA + r16) * H_DIM + q4 * 8;
        xa[0] = *(const float4*)(pA);
        xa[1] = *(const float4*)(pA + 4);
        xa[2] = *(const float4*)(pA + 32);
        xa[3] = *(const float4*)(pA + 36);
        const float* pB = pA + 16 * H_DIM;                      // c1: tt0,nt1
        xb[0] = *(const float4*)(pB);
        xb[1] = *(const float4*)(pB + 4);
        xb[2] = *(const float4*)(pB + 32);
        xb[3] = *(const float4*)(pB + 36);
    }

    // ===================== phase A: compose =====================
    float am[2][8];
    #pragma unroll
    for (int kh = 0; kh < 2; ++kh)
        #pragma unroll
        for (int e = 0; e < 8; ++e)
            am[kh][e] = M[(kh * 32 + q4 * 8 + e) * H_DIM + w * 16 + r16];

    if (t < NUM_ROT) {
        float sv, cv;
        sincosf(thetas[t] * theta_scale[0], &sv, &cv);
        csh[2 * t] = cv; csh[2 * t + 1] = sv;
    }
    if (t < 2 * NUM_ROT) prs[t] = (int)pairs[t];
    #pragma unroll
    for (int q = 0; q < 17; ++q) Rf[t + q * 256] = 0.0f;
    __syncthreads();

    // Givens rotations as column ops — row-local => barrier-free loop
    if (t < H_DIM) {
        float* myrow = &Rf[t * RF_STRIDE];
        myrow[t] = 1.0f;
        #pragma unroll
        for (int k = 0; k < NUM_ROT; ++k) {
            const int   i = prs[2 * k], j = prs[2 * k + 1];
            const float c = csh[2 * k], s = csh[2 * k + 1];
            const float ri = myrow[i], rj = myrow[j];
            if (i == j) {
                myrow[i] = c * ri;                    // chained .at corner case
            } else {
                myrow[i] =  c * ri + s * rj;
                myrow[j] = -s * ri + c * rj;
            }
        }
    }
    __syncthreads();

    // compose-GEMM on matrix pipe: D = M^T(A) x R^T(B) = final^T
    {
        bf16x8 ca[2];
        #pragma unroll
        for (int kh = 0; kh < 2; ++kh)
            ca[kh] = cvt8(make_float4(am[kh][0], am[kh][1], am[kh][2], am[kh][3]),
                          make_float4(am[kh][4], am[kh][5], am[kh][6], am[kh][7]));
        f32x4 dacc[4];
        #pragma unroll
        for (int j = 0; j < 4; ++j) {
            f32x4 z = {0.f, 0.f, 0.f, 0.f};
            #pragma unroll
            for (int kh = 0; kh < 2; ++kh) {
                const float* rp = &Rf[(j * 16 + r16) * RF_STRIDE + kh * 32 + q4 * 8];
                const float4 f0 = *(const float4*)(rp);
                const float4 f1 = *(const float4*)(rp + 4);
                z = __builtin_amdgcn_mfma_f32_16x16x32_bf16(ca[kh], cvt8(f0, f1),
                                                            z, 0, 0, 0);
            }
            dacc[j] = z;
        }
        // D[f][k] -> Rt_s[p][k], p = (f&1)*32 + f>>1  ([evens|odds] perm)
        #pragma unroll
        for (int j = 0; j < 4; ++j) {
            #pragma unroll
            for (int r = 0; r < 4; ++r) {
                const int f = w * 16 + q4 * 4 + r;       // C/D layout row
                const int p = ((f & 1) << 5) | (f >> 1);
                Rt_s[p * RT_STRIDE + j * 16 + r16] = f2bf(dacc[j][r]);
            }
        }
    }

    // sin/cos for ALL tiles in regs before the overlay barrier
    const int srl = t >> 5;          // 0..7
    const int sf  = t & 31;          // 0..31
    float svv[TILES], cvv[TILES];
    {
        const float fr = inv_freq[sf];
        #pragma unroll
        for (int tt = 0; tt < TILES; ++tt) {
            const int pos = ((bid + tt * nb) * 8 + srl) & (SEQ - 1);
            sincosf((float)pos * fr, &svv[tt], &cvv[tt]);
        }
    }
    __syncthreads();                 // Rt_s complete; Rf dead => overlay ok

    // ===================== phase B =====================
    #pragma unroll
    for (int tt = 0; tt < TILES; ++tt) {
        snc[tt * 512 + srl * 64 + sf]      = svv[tt];
        snc[tt * 512 + srl * 64 + 32 + sf] = cvv[tt];
    }
    bf16x8 afr[4][2];
    #pragma unroll
    for (int mt = 0; mt < 4; ++mt)
        #pragma unroll
        for (int kh = 0; kh < 2; ++kh)
            afr[mt][kh] = *(const bf16x8*)(
                &Rt_s[(mt * 16 + r16) * RT_STRIDE + kh * 32 + q4 * 8]);
    __syncthreads();                 // snc visible

    // 8 chunks = (tile, nt); 2-deep pipeline: xa=current, xb=next.
    #pragma unroll
    for (int c = 0; c < 2 * TILES; ++c) {
        const int tt = c >> 1, nt = c & 1;
        const size_t row0 = (size_t)(bid + tt * nb) * HVPB + w * 32 + nt * 16;

        // prefetch chunk c+2 into the slot being vacated this iteration
        float4 xn[4];
        if (c + 2 < 2 * TILES) {
            const int c2 = c + 2;
            const int tt2 = c2 >> 1, nt2 = c2 & 1;
            const size_t r2 = (size_t)(bid + tt2 * nb) * HVPB + w * 32 + nt2 * 16;
            const float* rp = x + (r2 + r16) * H_DIM + q4 * 8;
            xn[0] = *(const float4*)(rp);
            xn[1] = *(const float4*)(rp + 4);
            xn[2] = *(const float4*)(rp + 32);
            xn[3] = *(const float4*)(rp + 36);
        }

        // cvt current chunk (xa) to B-frags
        const bf16x8 b0 = cvt8(xa[0], xa[1]);
        const bf16x8 b1 = cvt8(xa[2], xa[3]);

        // MFMA
        f32x4 acc[4];
        #pragma unroll
        for (int mt = 0; mt < 4; ++mt) {
            f32x4 z = {0.0f, 0.0f, 0.0f, 0.0f};
            z = __builtin_amdgcn_mfma_f32_16x16x32_bf16(afr[mt][0], b0, z, 0, 0, 0);
            z = __builtin_amdgcn_mfma_f32_16x16x32_bf16(afr[mt][1], b1, z, 0, 0, 0);
            acc[mt] = z;
        }

        // RoPE in-register; direct full-line float4 stores
        const int pl = tt * 512 + (w * 2 + nt) * 64;
        float* op = out + (row0 + r16) * H_DIM;
        #pragma unroll
        for (int half = 0; half < 2; ++half) {
            const int p0 = half * 16 + q4 * 4;
            const float4 sn = *(const float4*)(&snc[pl + p0]);
            const float4 cs = *(const float4*)(&snc[pl + 32 + p0]);
            const f32x4 a1 = acc[half];
            const f32x4 a2 = acc[half + 2];
            float4 olo, ohi;
            olo.x = a1.x * cs.x - a2.x * sn.x;
            olo.y = a1.y * cs.y - a2.y * sn.y;
            olo.z = a1.z * cs.z - a2.z * sn.z;
            olo.w = a1.w * cs.w - a2.w * sn.w;
            ohi.x = a1.x * sn.x + a2.x * cs.x;
            ohi.y = a1.y * sn.y + a2.y * cs.y;
            ohi.z = a1.z * sn.z + a2.z * cs.z;
            ohi.w = a1.w * sn.w + a2.w * cs.w;
            *(float4*)(op + p0)      = olo;
            *(float4*)(op + 32 + p0) = ohi;
        }

        // rotate pipeline: xa <- xb, xb <- xn
        #pragma unroll
        for (int i = 0; i < 4; ++i) { xa[i] = xb[i]; }
        if (c + 2 < 2 * TILES) {
            #pragma unroll
            for (int i = 0; i < 4; ++i) xb[i] = xn[i];
        }
    }
}

// ---------------------------------------------------------------------------
extern "C" void kernel_launch(void* const* d_in, const int* in_sizes, int n_in,
                              void* d_out, int out_size, void* d_ws, size_t ws_size,
                              hipStream_t stream)
{
    const float* x      = (const float*)d_in[0];
    const float* thetas = (const float*)d_in[1];
    const float* pairs  = (const float*)d_in[2];
    const float* tscale = (const float*)d_in[3];
    const float* M      = (const float*)d_in[4];
    const float* invf   = (const float*)d_in[5];
    float* out = (float*)d_out;

    const int n_hv   = in_sizes[0] / H_DIM;          // B*S*N_HEAD = 262144
    const int blocks = n_hv / (HVPB * TILES);        // 512
    rope_fused_kernel<<<blocks, 256, 0, stream>>>(x, thetas, pairs, tscale,
                                                  M, invf, out, blocks);
}

// Round 17
// 26.580 us; speedup vs baseline: 1.1277x; 1.1277x over previous
//
#include <hip/hip_runtime.h>
#include <hip/hip_bf16.h>
#include <math.h>

// Problem constants (fixed by the reference's setup_inputs)
#define N_STATE 1024
#define N_HEAD  16
#define H_DIM   64          // N_STATE / N_HEAD
#define NUM_ROT 8
#define SEQ     4096
#define HVPB    128         // head-vectors per tile
#define TILES   2           // tiles per block (swept 1/2/4: 2 is optimal)

typedef __attribute__((ext_vector_type(8))) short bf16x8;
typedef __attribute__((ext_vector_type(4))) float f32x4;

// scalar float -> bf16 (round-to-nearest-even) — cold path
__device__ __forceinline__ unsigned short f2bf(float f) {
    union { float f; unsigned u; } v; v.f = f;
    unsigned r = v.u + 0x7fffu + ((v.u >> 16) & 1u);
    return (unsigned short)(r >> 16);
}
// packed pair convert via v_cvt_pk_bf16_f32 — hot path
__device__ __forceinline__ unsigned cvtpk(float a, float b) {
    union { __hip_bfloat162 h; unsigned u; } p;
    p.h = __float22bfloat162_rn(make_float2(a, b));
    return p.u;
}
__device__ __forceinline__ bf16x8 cvt8(const float4 lo, const float4 hi) {
    union { bf16x8 v; unsigned u[4]; } r;
    r.u[0] = cvtpk(lo.x, lo.y);
    r.u[1] = cvtpk(lo.z, lo.w);
    r.u[2] = cvtpk(hi.x, hi.y);
    r.u[3] = cvtpk(hi.z, hi.w);
    return r.v;
}

#define RF_STRIDE 68   // floats per row of Rf (64 + 4 pad)
#define RT_STRIDE 72   // shorts per row of Rt_s
// Static LDS layout (bytes):
//   [0     , 17408) Rf f32[64][68] (compose only) | overlay: snc f32[2][8][64] at [0,4096)
//   [17408 , 26624) Rt_s bf16[64][72]  permuted R^T, live whole kernel
//   [26624 , 26688) csh: 8 x (cos,sin)
//   [26688 , 26752) prs: 16 ints
#define SM_TOTAL 26752

// ---------------------------------------------------------------------------
// FINAL (r11 structure — best measured: 26.7us, 5.03 TB/s ≈ 80% of d2d ceiling)
//  entry: chunks 0,1 x loads issued immediately (compose hides latency).
//  A) per-block redundant compose: M direct from global (L2-hot), Givens
//     barrier-free (row-local), R@M on matrix pipe, permuted bf16 R^T to LDS.
//  B) 2 tiles x 2 chunks: B-frags direct from global (contiguous-in-K per
//     lane), packed cvt_pk, MFMA, in-register RoPE (permuted features =>
//     4 consecutive out cols/acc tile), full-line float4 stores; c+2 rolling
//     prefetch.
// Falsified alternatives: NT stores (WRITE inflation), TILES=1/4, 512-thr
// blocks, 5 blk/CU, entry-4 loads, LDS staging either direction, 2-barrier
// compose (races).
// ---------------------------------------------------------------------------
__global__ __launch_bounds__(256, 4)
void rope_fused_kernel(const float* __restrict__ x,
                       const float* __restrict__ thetas,
                       const float* __restrict__ pairs,
                       const float* __restrict__ theta_scale,
                       const float* __restrict__ M,
                       const float* __restrict__ inv_freq,
                       float* __restrict__ out,
                       int nb)                       // blocks in grid
{
    __shared__ __align__(16) char smem[SM_TOTAL];
    float*          Rf   = (float*)(smem);
    unsigned short* Rt_s = (unsigned short*)(smem + 17408);
    float*          csh  = (float*)(smem + 26624);
    int*            prs  = (int*)(smem + 26688);
    float*          snc  = (float*)(smem);                    // overlay (Rf dead)

    const int t   = threadIdx.x;
    const int w   = t >> 6;
    const int l   = t & 63;
    const int r16 = l & 15;
    const int q4  = l >> 4;
    const int bid = blockIdx.x;

    // ---- entry: issue x loads for chunks 0 and 1 (compose hides latency) ----
    float4 xa[4], xb[4];
    {
        const size_t rA = (size_t)bid * HVPB + w * 32;          // c0: tt0,nt0
        const float* pA = x + (rA + r16) * H_DIM + q4 * 8;
        xa[0] = *(const float4*)(pA);
        xa[1] = *(const float4*)(pA + 4);
        xa[2] = *(const float4*)(pA + 32);
        xa[3] = *(const float4*)(pA + 36);
        const size_t rB = rA + 16;                              // c1: tt0,nt1
        const float* pB = x + (rB + r16) * H_DIM + q4 * 8;
        xb[0] = *(const float4*)(pB);
        xb[1] = *(const float4*)(pB + 4);
        xb[2] = *(const float4*)(pB + 32);
        xb[3] = *(const float4*)(pB + 36);
    }

    // ===================== phase A: compose =====================
    float am[2][8];
    #pragma unroll
    for (int kh = 0; kh < 2; ++kh)
        #pragma unroll
        for (int e = 0; e < 8; ++e)
            am[kh][e] = M[(kh * 32 + q4 * 8 + e) * H_DIM + w * 16 + r16];

    if (t < NUM_ROT) {
        float sv, cv;
        sincosf(thetas[t] * theta_scale[0], &sv, &cv);
        csh[2 * t] = cv; csh[2 * t + 1] = sv;
    }
    if (t < 2 * NUM_ROT) prs[t] = (int)pairs[t];
    #pragma unroll
    for (int q = 0; q < 17; ++q) Rf[t + q * 256] = 0.0f;
    __syncthreads();

    // Givens rotations as column ops — row-local => barrier-free loop
    if (t < H_DIM) {
        float* myrow = &Rf[t * RF_STRIDE];
        myrow[t] = 1.0f;
        #pragma unroll
        for (int k = 0; k < NUM_ROT; ++k) {
            const int   i = prs[2 * k], j = prs[2 * k + 1];
            const float c = csh[2 * k], s = csh[2 * k + 1];
            const float ri = myrow[i], rj = myrow[j];
            if (i == j) {
                myrow[i] = c * ri;                    // chained .at corner case
            } else {
                myrow[i] =  c * ri + s * rj;
                myrow[j] = -s * ri + c * rj;
            }
        }
    }
    __syncthreads();

    // compose-GEMM on matrix pipe: D = M^T(A) x R^T(B) = final^T
    {
        bf16x8 ca[2];
        #pragma unroll
        for (int kh = 0; kh < 2; ++kh)
            ca[kh] = cvt8(make_float4(am[kh][0], am[kh][1], am[kh][2], am[kh][3]),
                          make_float4(am[kh][4], am[kh][5], am[kh][6], am[kh][7]));
        f32x4 dacc[4];
        #pragma unroll
        for (int j = 0; j < 4; ++j) {
            f32x4 z = {0.f, 0.f, 0.f, 0.f};
            #pragma unroll
            for (int kh = 0; kh < 2; ++kh) {
                const float* rp = &Rf[(j * 16 + r16) * RF_STRIDE + kh * 32 + q4 * 8];
                const float4 f0 = *(const float4*)(rp);
                const float4 f1 = *(const float4*)(rp + 4);
                z = __builtin_amdgcn_mfma_f32_16x16x32_bf16(ca[kh], cvt8(f0, f1),
                                                            z, 0, 0, 0);
            }
            dacc[j] = z;
        }
        // D[f][k] -> Rt_s[p][k], p = (f&1)*32 + f>>1  ([evens|odds] perm)
        #pragma unroll
        for (int j = 0; j < 4; ++j) {
            #pragma unroll
            for (int r = 0; r < 4; ++r) {
                const int f = w * 16 + q4 * 4 + r;       // C/D layout row
                const int p = ((f & 1) << 5) | (f >> 1);
                Rt_s[p * RT_STRIDE + j * 16 + r16] = f2bf(dacc[j][r]);
            }
        }
    }

    // sin/cos for BOTH tiles in regs before the overlay barrier
    const int srl = t >> 5;          // 0..7
    const int sf  = t & 31;          // 0..31
    float svv[TILES], cvv[TILES];
    {
        const float fr = inv_freq[sf];
        #pragma unroll
        for (int tt = 0; tt < TILES; ++tt) {
            const int pos = ((bid + tt * nb) * 8 + srl) & (SEQ - 1);
            sincosf((float)pos * fr, &svv[tt], &cvv[tt]);
        }
    }
    __syncthreads();                 // Rt_s complete; Rf dead => overlay ok

    // ===================== phase B =====================
    #pragma unroll
    for (int tt = 0; tt < TILES; ++tt) {
        snc[tt * 512 + srl * 64 + sf]      = svv[tt];
        snc[tt * 512 + srl * 64 + 32 + sf] = cvv[tt];
    }
    bf16x8 afr[4][2];
    #pragma unroll
    for (int mt = 0; mt < 4; ++mt)
        #pragma unroll
        for (int kh = 0; kh < 2; ++kh)
            afr[mt][kh] = *(const bf16x8*)(
                &Rt_s[(mt * 16 + r16) * RT_STRIDE + kh * 32 + q4 * 8]);
    __syncthreads();                 // snc visible

    // 4 chunks = (tile, nt); 2-deep pipeline: xa=current, xb=next.
    #pragma unroll
    for (int c = 0; c < 2 * TILES; ++c) {
        const int tt = c >> 1, nt = c & 1;
        const size_t row0 = (size_t)(bid + tt * nb) * HVPB + w * 32 + nt * 16;

        // prefetch chunk c+2 into the slot being vacated this iteration
        float4 xn[4];
        if (c + 2 < 2 * TILES) {
            const int c2 = c + 2;
            const int tt2 = c2 >> 1, nt2 = c2 & 1;
            const size_t r2 = (size_t)(bid + tt2 * nb) * HVPB + w * 32 + nt2 * 16;
            const float* rp = x + (r2 + r16) * H_DIM + q4 * 8;
            xn[0] = *(const float4*)(rp);
            xn[1] = *(const float4*)(rp + 4);
            xn[2] = *(const float4*)(rp + 32);
            xn[3] = *(const float4*)(rp + 36);
        }

        // cvt current chunk (xa) to B-frags
        const bf16x8 b0 = cvt8(xa[0], xa[1]);
        const bf16x8 b1 = cvt8(xa[2], xa[3]);

        // MFMA
        f32x4 acc[4];
        #pragma unroll
        for (int mt = 0; mt < 4; ++mt) {
            f32x4 z = {0.0f, 0.0f, 0.0f, 0.0f};
            z = __builtin_amdgcn_mfma_f32_16x16x32_bf16(afr[mt][0], b0, z, 0, 0, 0);
            z = __builtin_amdgcn_mfma_f32_16x16x32_bf16(afr[mt][1], b1, z, 0, 0, 0);
            acc[mt] = z;
        }

        // RoPE in-register; direct full-line float4 stores
        const int pl = tt * 512 + (w * 2 + nt) * 64;
        float* op = out + (row0 + r16) * H_DIM;
        #pragma unroll
        for (int half = 0; half < 2; ++half) {
            const int p0 = half * 16 + q4 * 4;
            const float4 sn = *(const float4*)(&snc[pl + p0]);
            const float4 cs = *(const float4*)(&snc[pl + 32 + p0]);
            const f32x4 a1 = acc[half];
            const f32x4 a2 = acc[half + 2];
            float4 olo, ohi;
            olo.x = a1.x * cs.x - a2.x * sn.x;
            olo.y = a1.y * cs.y - a2.y * sn.y;
            olo.z = a1.z * cs.z - a2.z * sn.z;
            olo.w = a1.w * cs.w - a2.w * sn.w;
            ohi.x = a1.x * sn.x + a2.x * cs.x;
            ohi.y = a1.y * sn.y + a2.y * cs.y;
            ohi.z = a1.z * sn.z + a2.z * cs.z;
            ohi.w = a1.w * sn.w + a2.w * cs.w;
            *(float4*)(op + p0)      = olo;
            *(float4*)(op + 32 + p0) = ohi;
        }

        // rotate pipeline: xa <- xb, xb <- xn
        #pragma unroll
        for (int i = 0; i < 4; ++i) { xa[i] = xb[i]; }
        if (c + 2 < 2 * TILES) {
            #pragma unroll
            for (int i = 0; i < 4; ++i) xb[i] = xn[i];
        }
    }
}

// ---------------------------------------------------------------------------
extern "C" void kernel_launch(void* const* d_in, const int* in_sizes, int n_in,
                              void* d_out, int out_size, void* d_ws, size_t ws_size,
                              hipStream_t stream)
{
    const float* x      = (const float*)d_in[0];
    const float* thetas = (const float*)d_in[1];
    const float* pairs  = (const float*)d_in[2];
    const float* tscale = (const float*)d_in[3];
    const float* M      = (const float*)d_in[4];
    const float* invf   = (const float*)d_in[5];
    float* out = (float*)d_out;

    const int n_hv   = in_sizes[0] / H_DIM;          // B*S*N_HEAD = 262144
    const int blocks = n_hv / (HVPB * TILES);        // 1024
    rope_fused_kernel<<<blocks, 256, 0, stream>>>(x, thetas, pairs, tscale,
                                                  M, invf, out, blocks);
}